// Round 2
// baseline (1030.174 us; speedup 1.0000x reference)
//
#include <hip/hip_runtime.h>
#include <hip/hip_bf16.h>
#include <math.h>

using bf16 = __hip_bfloat16;
typedef __attribute__((ext_vector_type(8))) short short8;
typedef __attribute__((ext_vector_type(4))) float f32x4;

constexpr int Bc = 4, Sc = 4096, Dc = 1024, Hc = 16, DHc = 64, Fc = 64, DFFc = 4096;
constexpr float EPS_LN_C = 1e-5f, EPS_ATTN_C = 1e-6f;
constexpr int KVSPLIT = 16;

static __device__ __forceinline__ float b2f(bf16 v) { return __bfloat162float(v); }
static __device__ __forceinline__ bf16 f2b(float f) { return __float2bfloat16(f); }

// ---------------- block reduction (256 threads, wave64) ----------------
__device__ float block_reduce_sum(float v) {
  __shared__ float red[4];
  int lane = threadIdx.x & 63, wid = threadIdx.x >> 6;
#pragma unroll
  for (int off = 32; off > 0; off >>= 1) v += __shfl_down(v, off, 64);
  __syncthreads();
  if (lane == 0) red[wid] = v;
  __syncthreads();
  return red[0] + red[1] + red[2] + red[3];
}

// ---------------- LayerNorm: one block per row (D=1024) ----------------
__global__ void ln_kernel(const float* __restrict__ x, const float* __restrict__ g,
                          const float* __restrict__ bta, bf16* __restrict__ out) {
  int row = blockIdx.x;
  const float* xr = x + (size_t)row * Dc;
  int t = threadIdx.x;
  float v[4];
#pragma unroll
  for (int i = 0; i < 4; ++i) v[i] = xr[t + 256 * i];
  float s = block_reduce_sum(v[0] + v[1] + v[2] + v[3]);
  float mu = s * (1.f / Dc);
  float vs = 0.f;
#pragma unroll
  for (int i = 0; i < 4; ++i) { float d = v[i] - mu; vs += d * d; }
  vs = block_reduce_sum(vs);
  float rstd = rsqrtf(vs * (1.f / Dc) + EPS_LN_C);
  bf16* orow = out + (size_t)row * Dc;
#pragma unroll
  for (int i = 0; i < 4; ++i) {
    int c = t + 256 * i;
    orow[c] = f2b((v[i] - mu) * rstd * g[c] + bta[c]);
  }
}

// ------------- transpose + convert: in f32 [K,N] -> out bf16 [N,K] -------------
__global__ void tcvt_kernel(const float* __restrict__ in, bf16* __restrict__ out,
                            int K, int N) {
  __shared__ float t[32][33];
  int n0 = blockIdx.x * 32, k0 = blockIdx.y * 32;
  int tid = threadIdx.x;
#pragma unroll
  for (int i = 0; i < 4; ++i) {
    int idx = tid + 256 * i;
    int r = idx >> 5, c = idx & 31;
    t[r][c] = in[(size_t)(k0 + r) * N + n0 + c];
  }
  __syncthreads();
#pragma unroll
  for (int i = 0; i < 4; ++i) {
    int idx = tid + 256 * i;
    int r = idx >> 5, c = idx & 31;
    out[(size_t)(n0 + r) * K + k0 + c] = f2b(t[c][r]);
  }
}

// ================= 256x256 8-phase MFMA GEMM (T2+T3+T4+T5) =================
// C[M,N] = A(bf16)[M,lda] * Bt(bf16)[N,ldbt]^T
// 512 threads = 8 waves (2M x 4N), per-wave 128x64 output, BK=64, 2-tile LDS dbuf
// (128 KiB). LDS XOR-swizzle byte^=((row&7)<<4) applied via pre-swizzled global
// source (linear global_load_lds dest) + swizzled ds_read address.
// vmcnt(0) only at phases 4 and 8 (4-phase lead on all stages).
// EPI: 0 bf16 store | 1 f32 +bias+res | 2 bf16 gelu(+bias) | 3 f32 +(bias?)+res
//      4 QKV split: col c -> outB + (c>>10)*TOK*1024, col c&1023

template <int MH, int NH, bool LOADA>
static __device__ __forceinline__ void phase_mfma(
    const ushort* __restrict__ ab, const ushort* __restrict__ bb,
    int wr, int wc, int mrow, int cs0, int cs1,
    short8 af[4][2], f32x4 acc[8][4]) {
  if (LOADA) {
#pragma unroll
    for (int i2 = 0; i2 < 4; ++i2) {
      const ushort* p = ab + (wr * 128 + MH * 64 + i2 * 16 + mrow) * 64;
      af[i2][0] = *(const short8*)(p + cs0);
      af[i2][1] = *(const short8*)(p + cs1);
    }
  }
  short8 bf2[2][2];
#pragma unroll
  for (int j2 = 0; j2 < 2; ++j2) {
    const ushort* p = bb + (wc * 64 + NH * 32 + j2 * 16 + mrow) * 64;
    bf2[j2][0] = *(const short8*)(p + cs0);
    bf2[j2][1] = *(const short8*)(p + cs1);
  }
  __builtin_amdgcn_s_barrier();
  asm volatile("s_waitcnt lgkmcnt(0)");
  __builtin_amdgcn_s_setprio(1);
#pragma unroll
  for (int i2 = 0; i2 < 4; ++i2)
#pragma unroll
    for (int j2 = 0; j2 < 2; ++j2) {
      acc[MH * 4 + i2][NH * 2 + j2] = __builtin_amdgcn_mfma_f32_16x16x32_bf16(
          af[i2][0], bf2[j2][0], acc[MH * 4 + i2][NH * 2 + j2], 0, 0, 0);
      acc[MH * 4 + i2][NH * 2 + j2] = __builtin_amdgcn_mfma_f32_16x16x32_bf16(
          af[i2][1], bf2[j2][1], acc[MH * 4 + i2][NH * 2 + j2], 0, 0, 0);
    }
  __builtin_amdgcn_s_setprio(0);
}

template <int EPI>
__global__ __launch_bounds__(512, 2)
void mgemm256_kernel(const ushort* __restrict__ A, const ushort* __restrict__ Bt,
                     const float* __restrict__ bias, const float* __restrict__ res,
                     float* __restrict__ outF, bf16* __restrict__ outB,
                     int M, int N, int K, int lda, int ldbt) {
  __shared__ ushort As[2][256 * 64];
  __shared__ ushort Bs[2][256 * 64];
  const int tid = threadIdx.x;
  const int wave = tid >> 6, lane = tid & 63;
  const int wr = wave >> 2, wc = wave & 3;
  const int mrow = lane & 15, quad = lane >> 4;

  int nn = gridDim.x, nm = gridDim.y;
  int bid = blockIdx.y * nn + blockIdx.x;
  int mtile, ntile;
  if ((nm & 7) == 0) {          // XCD swizzle (bijection; perf-only heuristic)
    int xcd = bid & 7, s = bid >> 3;
    int mpx = nm >> 3;
    int mloc = s / nn;
    ntile = s - mloc * nn;
    mtile = xcd * mpx + mloc;
  } else { mtile = blockIdx.y; ntile = blockIdx.x; }
  const int row0 = mtile * 256, col0 = ntile * 256;

  // ---- staging: linear LDS dest (l*8192B + tid*16B), inverse-swizzled source.
  // linear byte L -> logical row = l*64 + (tid>>3), logical col bytes =
  // ((tid&7)*16) ^ ((row&7)<<4)
  const int srow = tid >> 3;
  const int scol = ((((tid & 7) * 16) ^ ((srow & 7) << 4)) >> 1);  // ushort units
  const ushort* aSrc[4];
  const ushort* bSrc[4];
#pragma unroll
  for (int l = 0; l < 4; ++l) {
    aSrc[l] = A + (size_t)(row0 + l * 64 + srow) * lda + scol;
    bSrc[l] = Bt + (size_t)(col0 + l * 64 + srow) * ldbt + scol;
  }
  const int dstoff = tid * 8;  // ushort units

  auto stage = [&](int kt, int b) {
    const int ko = kt * 64;
#pragma unroll
    for (int l = 0; l < 4; ++l)
      __builtin_amdgcn_global_load_lds(
          (const __attribute__((address_space(1))) void*)(aSrc[l] + ko),
          (__attribute__((address_space(3))) void*)(&As[b][l * 4096 + dstoff]), 16, 0, 0);
#pragma unroll
    for (int l = 0; l < 4; ++l)
      __builtin_amdgcn_global_load_lds(
          (const __attribute__((address_space(1))) void*)(bSrc[l] + ko),
          (__attribute__((address_space(3))) void*)(&Bs[b][l * 4096 + dstoff]), 16, 0, 0);
  };

  // swizzled ds_read column offsets (ushort units): (quad*8 + step*32) ^ ((mrow&7)<<3)
  const int cs0 = (quad * 8) ^ ((mrow & 7) << 3);
  const int cs1 = (quad * 8 + 32) ^ ((mrow & 7) << 3);

  f32x4 acc[8][4] = {};
  short8 af[4][2];

  // prologue: tile 0 -> buf0, full safe drain (once)
  stage(0, 0);
  __syncthreads();   // compiler emits s_waitcnt vmcnt(0) lgkmcnt(0) + s_barrier

  const int NI = K >> 7;  // 2 K-tiles (128 of K) per iteration
  for (int it = 0; it < NI; ++it) {
    // phases 1-4: compute tile 2it from buf0; stage tile 2it+1 -> buf1 (phase 1)
    stage(2 * it + 1, 1);
    phase_mfma<0, 0, true >(As[0], Bs[0], wr, wc, mrow, cs0, cs1, af, acc);
    __builtin_amdgcn_s_barrier();
    phase_mfma<0, 1, false>(As[0], Bs[0], wr, wc, mrow, cs0, cs1, af, acc);
    __builtin_amdgcn_s_barrier();
    phase_mfma<1, 0, true >(As[0], Bs[0], wr, wc, mrow, cs0, cs1, af, acc);
    __builtin_amdgcn_s_barrier();
    phase_mfma<1, 1, false>(As[0], Bs[0], wr, wc, mrow, cs0, cs1, af, acc);
    asm volatile("s_waitcnt vmcnt(0)" ::: "memory");  // tile 2it+1 landed
    __builtin_amdgcn_s_barrier();
    // phases 5-8: compute tile 2it+1 from buf1; stage tile 2it+2 -> buf0 (phase 5)
    if (it + 1 < NI) stage(2 * it + 2, 0);
    phase_mfma<0, 0, true >(As[1], Bs[1], wr, wc, mrow, cs0, cs1, af, acc);
    __builtin_amdgcn_s_barrier();
    phase_mfma<0, 1, false>(As[1], Bs[1], wr, wc, mrow, cs0, cs1, af, acc);
    __builtin_amdgcn_s_barrier();
    phase_mfma<1, 0, true >(As[1], Bs[1], wr, wc, mrow, cs0, cs1, af, acc);
    __builtin_amdgcn_s_barrier();
    phase_mfma<1, 1, false>(As[1], Bs[1], wr, wc, mrow, cs0, cs1, af, acc);
    asm volatile("s_waitcnt vmcnt(0)" ::: "memory");  // tile 2it+2 landed
    __builtin_amdgcn_s_barrier();
  }

  // epilogue
#pragma unroll
  for (int i = 0; i < 8; ++i) {
#pragma unroll
    for (int j = 0; j < 4; ++j) {
      int rb = row0 + wr * 128 + i * 16 + quad * 4;
      int c = col0 + wc * 64 + j * 16 + mrow;
#pragma unroll
      for (int r = 0; r < 4; ++r) {
        int rr = rb + r;
        float v = acc[i][j][r];
        if (EPI == 1 || EPI == 2) v += bias[c];
        if (EPI == 3) { if (bias) v += bias[c]; }
        if (EPI == 2) v = 0.5f * v * (1.f + erff(v * 0.70710678118654752f));
        if (EPI == 1 || EPI == 3) v += res[(size_t)rr * N + c];
        if (EPI == 4) {
          outB[((size_t)(c >> 10) * (size_t)(Bc * Sc) + rr) * 1024 + (c & 1023)] = f2b(v);
        } else if (EPI == 0 || EPI == 2) {
          outB[(size_t)rr * N + c] = f2b(v);
        } else {
          outF[(size_t)rr * N + c] = v;
        }
      }
    }
  }
}

// ======== fm_mfma: per-head [256s x 64] @ projT[64f][64d]^T, relu+eps ========
__global__ __launch_bounds__(256, 2)
void fm_mfma(const ushort* __restrict__ qin, const ushort* __restrict__ pjt,
             bf16* __restrict__ qf) {
  __shared__ ushort As[256 * 64];   // [s_local][d]
  __shared__ ushort Bs[64 * 64];    // [f][d]
  int t = threadIdx.x;
  int wave = t >> 6, lane = t & 63;
  int mrow = lane & 15, quad = lane >> 4;
  int b = blockIdx.z, h = blockIdx.y, s0 = blockIdx.x * 256;
  const ushort* abase = qin + ((size_t)b * Sc + s0) * (Hc * DHc) + h * DHc;

#pragma unroll
  for (int i = 0; i < 8; ++i) {
    int c = t + 256 * i;
    int row = c >> 3, col = (c & 7) * 8;
    __builtin_amdgcn_global_load_lds(
        (const __attribute__((address_space(1))) void*)(abase + (size_t)row * (Hc * DHc) + col),
        (__attribute__((address_space(3))) void*)(As + c * 8), 16, 0, 0);
  }
#pragma unroll
  for (int i = 0; i < 2; ++i) {
    int c = t + 256 * i;
    __builtin_amdgcn_global_load_lds(
        (const __attribute__((address_space(1))) void*)(pjt + c * 8),
        (__attribute__((address_space(3))) void*)(Bs + c * 8), 16, 0, 0);
  }
  __syncthreads();

  f32x4 acc[4][4] = {};
#pragma unroll
  for (int step = 0; step < 2; ++step) {
    short8 af[4], bfv[4];
#pragma unroll
    for (int i = 0; i < 4; ++i)
      af[i] = *(const short8*)(As + (wave * 64 + i * 16 + mrow) * 64 + quad * 8 + step * 32);
#pragma unroll
    for (int j = 0; j < 4; ++j)
      bfv[j] = *(const short8*)(Bs + (j * 16 + mrow) * 64 + quad * 8 + step * 32);
#pragma unroll
    for (int i = 0; i < 4; ++i)
#pragma unroll
      for (int j = 0; j < 4; ++j)
        acc[i][j] = __builtin_amdgcn_mfma_f32_16x16x32_bf16(af[i], bfv[j], acc[i][j], 0, 0, 0);
  }

  size_t obase = ((size_t)(b * Hc + h)) * Sc + s0;
#pragma unroll
  for (int i = 0; i < 4; ++i) {
#pragma unroll
    for (int j = 0; j < 4; ++j) {
      int f = j * 16 + mrow;
#pragma unroll
      for (int r = 0; r < 4; ++r) {
        int s = wave * 64 + i * 16 + quad * 4 + r;
        float v = fmaxf(acc[i][j][r], 0.f) + EPS_ATTN_C;
        qf[(obase + s) * Fc + f] = f2b(v);
      }
    }
  }
}

// ======== kvp_mfma: split-K kf^T v (+ ksum) via LDS transpose ========
__global__ __launch_bounds__(256, 2)
void kvp_mfma(const ushort* __restrict__ kf, const ushort* __restrict__ v,
              float* __restrict__ kvp, float* __restrict__ ksump) {
  constexpr int LT = 72;
  __shared__ ushort kfT[64 * LT];   // [f][s]
  __shared__ ushort vT[64 * LT];    // [d][s]
  int t = threadIdx.x;
  int wave = t >> 6, lane = t & 63;
  int mrow = lane & 15, quad = lane >> 4;
  int split = blockIdx.x, bh = blockIdx.y;
  int b = bh >> 4, h = bh & 15;
  int sbase = split * (Sc / KVSPLIT);

  short8 ones, zero;
#pragma unroll
  for (int i = 0; i < 8; ++i) { ones[i] = (short)0x3F80; zero[i] = 0; }
  short8 bks = (mrow == 0) ? ones : zero;

  f32x4 acc[4] = {};
  f32x4 accks = {};

  for (int sc = 0; sc < Sc / KVSPLIT; sc += 64) {
    __syncthreads();
    int sl = t >> 2, c8 = (t & 3) * 8;
    const ushort* kp = kf + (((size_t)bh * Sc) + sbase + sc + sl) * Fc + c8;
    const ushort* vp = v + (((size_t)b * Sc) + sbase + sc + sl) * (Hc * DHc) + h * DHc + c8;
#pragma unroll
    for (int half = 0; half < 2; ++half) {
      short8 kv8 = *(const short8*)(kp + half * 32);
      short8 vv8 = *(const short8*)(vp + half * 32);
#pragma unroll
      for (int jj = 0; jj < 8; ++jj) {
        kfT[(c8 + half * 32 + jj) * LT + sl] = (ushort)kv8[jj];
        vT[(c8 + half * 32 + jj) * LT + sl] = (ushort)vv8[jj];
      }
    }
    __syncthreads();
#pragma unroll
    for (int step = 0; step < 2; ++step) {
      short8 af = *(const short8*)(kfT + (wave * 16 + mrow) * LT + quad * 8 + step * 32);
      short8 bfv[4];
#pragma unroll
      for (int j = 0; j < 4; ++j)
        bfv[j] = *(const short8*)(vT + (j * 16 + mrow) * LT + quad * 8 + step * 32);
#pragma unroll
      for (int j = 0; j < 4; ++j)
        acc[j] = __builtin_amdgcn_mfma_f32_16x16x32_bf16(af, bfv[j], acc[j], 0, 0, 0);
      accks = __builtin_amdgcn_mfma_f32_16x16x32_bf16(af, bks, accks, 0, 0, 0);
    }
  }

  size_t pbase = (size_t)bh * KVSPLIT + split;
#pragma unroll
  for (int j = 0; j < 4; ++j) {
    int d = j * 16 + mrow;
#pragma unroll
    for (int r = 0; r < 4; ++r) {
      int f = wave * 16 + quad * 4 + r;
      kvp[(pbase * 64 + f) * 64 + d] = acc[j][r];
    }
  }
  if (mrow == 0) {
#pragma unroll
    for (int r = 0; r < 4; ++r) {
      int f = wave * 16 + quad * 4 + r;
      ksump[pbase * 64 + f] = accks[r];
    }
  }
}

// ------- kv reduce: sums KVSPLIT partials -> kvt bf16 [d][f], ksum bf16 -------
__global__ void kvr_kernel(const float* __restrict__ kvp, const float* __restrict__ ksump,
                           bf16* __restrict__ kvt, bf16* __restrict__ ksum16) {
  int bh = blockIdx.x;
  int t = threadIdx.x;
#pragma unroll
  for (int i = 0; i < 16; ++i) {
    int idx = t + 256 * i;
    int f = idx >> 6, d = idx & 63;
    float s = 0.f;
#pragma unroll
    for (int j = 0; j < KVSPLIT; ++j)
      s += kvp[((size_t)bh * KVSPLIT + j) * 4096 + idx];
    kvt[((size_t)bh * 64 + d) * 64 + f] = f2b(s);
  }
  if (t < 64) {
    float s = 0.f;
#pragma unroll
    for (int j = 0; j < KVSPLIT; ++j)
      s += ksump[((size_t)bh * KVSPLIT + j) * 64 + t];
    ksum16[bh * 64 + t] = f2b(s);
  }
}

// ======== attn_mfma: per-head (qf @ kv) / (qf.ksum + eps) ========
__global__ __launch_bounds__(256, 2)
void attn_mfma(const ushort* __restrict__ qf, const ushort* __restrict__ kvt,
               const ushort* __restrict__ ksum16, bf16* __restrict__ attn) {
  __shared__ ushort As[256 * 64];   // [s_local][f]
  __shared__ ushort Bs[64 * 64];    // [d][f]
  int t = threadIdx.x;
  int wave = t >> 6, lane = t & 63;
  int mrow = lane & 15, quad = lane >> 4;
  int b = blockIdx.z, h = blockIdx.y, s0 = blockIdx.x * 256;
  int bh = b * Hc + h;
  const ushort* abase = qf + (((size_t)bh * Sc) + s0) * Fc;
  const ushort* bbase = kvt + (size_t)bh * 4096;

#pragma unroll
  for (int i = 0; i < 8; ++i) {
    int c = t + 256 * i;
    __builtin_amdgcn_global_load_lds(
        (const __attribute__((address_space(1))) void*)(abase + c * 8),
        (__attribute__((address_space(3))) void*)(As + c * 8), 16, 0, 0);
  }
#pragma unroll
  for (int i = 0; i < 2; ++i) {
    int c = t + 256 * i;
    __builtin_amdgcn_global_load_lds(
        (const __attribute__((address_space(1))) void*)(bbase + c * 8),
        (__attribute__((address_space(3))) void*)(Bs + c * 8), 16, 0, 0);
  }
  short8 zero;
#pragma unroll
  for (int i = 0; i < 8; ++i) zero[i] = 0;
  short8 ksf[2];
#pragma unroll
  for (int step = 0; step < 2; ++step) {
    short8 kv8 = *(const short8*)(ksum16 + bh * 64 + quad * 8 + step * 32);
    ksf[step] = (mrow == 0) ? kv8 : zero;
  }
  __syncthreads();

  f32x4 acc[4][4] = {};
  f32x4 accd[4] = {};
#pragma unroll
  for (int step = 0; step < 2; ++step) {
    short8 af[4], bfv[4];
#pragma unroll
    for (int i = 0; i < 4; ++i)
      af[i] = *(const short8*)(As + (wave * 64 + i * 16 + mrow) * 64 + quad * 8 + step * 32);
#pragma unroll
    for (int j = 0; j < 4; ++j)
      bfv[j] = *(const short8*)(Bs + (j * 16 + mrow) * 64 + quad * 8 + step * 32);
#pragma unroll
    for (int i = 0; i < 4; ++i) {
#pragma unroll
      for (int j = 0; j < 4; ++j)
        acc[i][j] = __builtin_amdgcn_mfma_f32_16x16x32_bf16(af[i], bfv[j], acc[i][j], 0, 0, 0);
      accd[i] = __builtin_amdgcn_mfma_f32_16x16x32_bf16(af[i], ksf[step], accd[i], 0, 0, 0);
    }
  }

#pragma unroll
  for (int i = 0; i < 4; ++i) {
    float inv[4];
#pragma unroll
    for (int r = 0; r < 4; ++r) {
      float den = __shfl(accd[i][r], lane & 48);
      inv[r] = 1.0f / (den + EPS_ATTN_C);
    }
#pragma unroll
    for (int j = 0; j < 4; ++j) {
      int d = j * 16 + mrow;
#pragma unroll
      for (int r = 0; r < 4; ++r) {
        int s = s0 + wave * 64 + i * 16 + quad * 4 + r;
        attn[((size_t)(b * Sc + s)) * (Hc * DHc) + h * DHc + d] = f2b(acc[i][j][r] * inv[r]);
      }
    }
  }
}

extern "C" void kernel_launch(void* const* d_in, const int* in_sizes, int n_in,
                              void* d_out, int out_size, void* d_ws, size_t ws_size,
                              hipStream_t stream) {
  const float* x     = (const float*)d_in[0];
  const float* ln1_g = (const float*)d_in[1];
  const float* ln1_b = (const float*)d_in[2];
  const float* wq    = (const float*)d_in[3];
  const float* wk    = (const float*)d_in[4];
  const float* wv    = (const float*)d_in[5];
  const float* proj  = (const float*)d_in[6];
  const float* wo    = (const float*)d_in[7];
  const float* bo    = (const float*)d_in[8];
  const float* ln2_g = (const float*)d_in[9];
  const float* ln2_b = (const float*)d_in[10];
  const float* w1    = (const float*)d_in[11];
  const float* b1    = (const float*)d_in[12];
  const float* w2    = (const float*)d_in[13];
  const float* b2    = (const float*)d_in[14];
  float* out = (float*)d_out;
  (void)ws_size; (void)in_sizes; (void)n_in; (void)out_size;

  const size_t TOK = (size_t)Bc * Sc;           // 16384
  const size_t REG = TOK * Dc * sizeof(bf16);   // 32 MB
  char* ws = (char*)d_ws;
  bf16* R0 = (bf16*)(ws + 0 * REG);             // h -> qf -> h2
  bf16* R1 = (bf16*)(ws + 1 * REG);             // q -> kf -> mid(lo)
  bf16* R2 = (bf16*)(ws + 2 * REG);             // k -> [kv partials] -> attn -> mid(hi)
  bf16* R3 = (bf16*)(ws + 3 * REG);             // v
  bf16* mid = R1;
  float* kvpart = (float*)R2;                                   // 16 MB (aliases R2)
  float* kspart = (float*)((char*)R2 + (size_t)64 * KVSPLIT * 4096 * 4);
  char* p = ws + 4 * REG;
  bf16* kvt   = (bf16*)p;                 p += (size_t)64 * 64 * 64 * 2;
  bf16* ksb16 = (bf16*)p;                 p += (size_t)64 * 64 * 2;
  bf16* pjt   = (bf16*)p;                 p += (size_t)64 * 64 * 2;
  bf16* wqt = (bf16*)p;                   p += (size_t)Dc * Dc * 2;   // wqt/wkt/wvt contiguous:
  bf16* wkt = (bf16*)p;                   p += (size_t)Dc * Dc * 2;   // single [3072][1024] Bt slab
  bf16* wvt = (bf16*)p;                   p += (size_t)Dc * Dc * 2;
  bf16* wot = (bf16*)p;                   p += (size_t)Dc * Dc * 2;
  bf16* w1t = (bf16*)p;                   p += (size_t)Dc * DFFc * 2;
  bf16* w2t = (bf16*)p;                   p += (size_t)Dc * DFFc * 2;

  dim3 blk(256);
  dim3 blk512(512);
  // 0. transpose+convert weights (and proj) to bf16 B^T form
  tcvt_kernel<<<dim3(Dc / 32, Dc / 32), blk, 0, stream>>>(wq, wqt, Dc, Dc);
  tcvt_kernel<<<dim3(Dc / 32, Dc / 32), blk, 0, stream>>>(wk, wkt, Dc, Dc);
  tcvt_kernel<<<dim3(Dc / 32, Dc / 32), blk, 0, stream>>>(wv, wvt, Dc, Dc);
  tcvt_kernel<<<dim3(Dc / 32, Dc / 32), blk, 0, stream>>>(wo, wot, Dc, Dc);
  tcvt_kernel<<<dim3(DFFc / 32, Dc / 32), blk, 0, stream>>>(w1, w1t, Dc, DFFc);
  tcvt_kernel<<<dim3(Dc / 32, DFFc / 32), blk, 0, stream>>>(w2, w2t, DFFc, Dc);
  tcvt_kernel<<<dim3(2, 2), blk, 0, stream>>>(proj, pjt, 64, 64);

  // 1. h = LN1(x) -> R0
  ln_kernel<<<dim3(TOK), blk, 0, stream>>>(x, ln1_g, ln1_b, R0);

  // 2. fused QKV: [TOK,1024] @ [3072,1024]^T -> split into R1,R2,R3 (EPI=4)
  dim3 gQKV(3072 / 256, TOK / 256);
  mgemm256_kernel<4><<<gQKV, blk512, 0, stream>>>((const ushort*)R0, (const ushort*)wqt,
                                                  nullptr, nullptr, nullptr, R1,
                                                  TOK, 3072, Dc, Dc, Dc);

  // 5-6. qf = fm(q): R1 -> R0 ; kf = fm(k): R2 -> R1
  dim3 gF(Sc / 256, Hc, Bc);
  fm_mfma<<<gF, blk, 0, stream>>>((const ushort*)R1, (const ushort*)pjt, R0);
  fm_mfma<<<gF, blk, 0, stream>>>((const ushort*)R2, (const ushort*)pjt, R1);

  // 7. kv partials + reduce
  kvp_mfma<<<dim3(KVSPLIT, Bc * Hc), blk, 0, stream>>>((const ushort*)R1, (const ushort*)R3,
                                                       kvpart, kspart);
  kvr_kernel<<<dim3(Bc * Hc), blk, 0, stream>>>(kvpart, kspart, kvt, ksb16);

  // 8. attn: qf(R0) x kvt -> R2
  attn_mfma<<<gF, blk, 0, stream>>>((const ushort*)R0, (const ushort*)kvt,
                                    (const ushort*)ksb16, R2);

  // 9. x2 = x + attn @ wo + bo -> d_out (f32)
  dim3 gD(Dc / 256, TOK / 256);
  mgemm256_kernel<1><<<gD, blk512, 0, stream>>>((const ushort*)R2, (const ushort*)wot, bo, x,
                                                out, nullptr, TOK, Dc, Dc, Dc, Dc);

  // 10. h2 = LN2(x2) -> R0
  ln_kernel<<<dim3(TOK), blk, 0, stream>>>(out, ln2_g, ln2_b, R0);

  // 11-12. FFN in two DFF halves (mid aliases R1+R2)
  dim3 gW1(2048 / 256, TOK / 256);
  mgemm256_kernel<2><<<gW1, blk512, 0, stream>>>((const ushort*)R0, (const ushort*)w1t, b1, nullptr,
                                                 nullptr, mid, TOK, 2048, Dc, Dc, Dc);
  mgemm256_kernel<3><<<gD, blk512, 0, stream>>>((const ushort*)mid, (const ushort*)w2t, b2, out,
                                                out, nullptr, TOK, Dc, 2048, 2048, DFFc);
  mgemm256_kernel<2><<<gW1, blk512, 0, stream>>>((const ushort*)R0, (const ushort*)(w1t + (size_t)2048 * Dc), b1 + 2048,
                                                 nullptr, nullptr, mid, TOK, 2048, Dc, Dc, Dc);
  mgemm256_kernel<3><<<gD, blk512, 0, stream>>>((const ushort*)mid, (const ushort*)(w2t + 2048), nullptr, out,
                                                out, nullptr, TOK, Dc, 2048, 2048, DFFc);
}

// Round 3
// 885.536 us; speedup vs baseline: 1.1633x; 1.1633x over previous
//
#include <hip/hip_runtime.h>
#include <hip/hip_bf16.h>
#include <math.h>

using bf16 = __hip_bfloat16;
typedef __attribute__((ext_vector_type(8))) short short8;
typedef __attribute__((ext_vector_type(4))) float f32x4;

constexpr int Bc = 4, Sc = 4096, Dc = 1024, Hc = 16, DHc = 64, Fc = 64, DFFc = 4096;
constexpr float EPS_LN_C = 1e-5f, EPS_ATTN_C = 1e-6f;
constexpr int KVSPLIT = 16;

static __device__ __forceinline__ float b2f(bf16 v) { return __bfloat162float(v); }
static __device__ __forceinline__ bf16 f2b(float f) { return __float2bfloat16(f); }

// ---------------- block reduction (256 threads, wave64) ----------------
__device__ float block_reduce_sum(float v) {
  __shared__ float red[4];
  int lane = threadIdx.x & 63, wid = threadIdx.x >> 6;
#pragma unroll
  for (int off = 32; off > 0; off >>= 1) v += __shfl_down(v, off, 64);
  __syncthreads();
  if (lane == 0) red[wid] = v;
  __syncthreads();
  return red[0] + red[1] + red[2] + red[3];
}

// ---------------- LayerNorm: one block per row (D=1024) ----------------
__global__ void ln_kernel(const float* __restrict__ x, const float* __restrict__ g,
                          const float* __restrict__ bta, bf16* __restrict__ out) {
  int row = blockIdx.x;
  const float* xr = x + (size_t)row * Dc;
  int t = threadIdx.x;
  float v[4];
#pragma unroll
  for (int i = 0; i < 4; ++i) v[i] = xr[t + 256 * i];
  float s = block_reduce_sum(v[0] + v[1] + v[2] + v[3]);
  float mu = s * (1.f / Dc);
  float vs = 0.f;
#pragma unroll
  for (int i = 0; i < 4; ++i) { float d = v[i] - mu; vs += d * d; }
  vs = block_reduce_sum(vs);
  float rstd = rsqrtf(vs * (1.f / Dc) + EPS_LN_C);
  bf16* orow = out + (size_t)row * Dc;
#pragma unroll
  for (int i = 0; i < 4; ++i) {
    int c = t + 256 * i;
    orow[c] = f2b((v[i] - mu) * rstd * g[c] + bta[c]);
  }
}

// ------------- transpose + convert: in f32 [K,N] -> out bf16 [N,K] -------------
__global__ void tcvt_kernel(const float* __restrict__ in, bf16* __restrict__ out,
                            int K, int N) {
  __shared__ float t[32][33];
  int n0 = blockIdx.x * 32, k0 = blockIdx.y * 32;
  int tid = threadIdx.x;
#pragma unroll
  for (int i = 0; i < 4; ++i) {
    int idx = tid + 256 * i;
    int r = idx >> 5, c = idx & 31;
    t[r][c] = in[(size_t)(k0 + r) * N + n0 + c];
  }
  __syncthreads();
#pragma unroll
  for (int i = 0; i < 4; ++i) {
    int idx = tid + 256 * i;
    int r = idx >> 5, c = idx & 31;
    out[(size_t)(n0 + r) * K + k0 + c] = f2b(t[c][r]);
  }
}

// ============ 256x256 MFMA GEMM, BK=32 4-slot ring, counted vmcnt ============
// C[M,N] = A(bf16)[M,lda] * Bt(bf16)[N,ldbt]^T
// 512 threads = 8 waves (2M x 4N), per-wave 128x64 output.
// LDS ring: 4 slots x (A[256][32] + B[256][32]) = 128 KiB. Sub-tile s consumed
// over 2 phases (16 MFMA each, MH=0/1; B-frags register-reused); sub-tile s+3
// staged during s's phases (2 global_load_lds/phase) into the slot freed after
// s-1. Wait entering s+1: vmcnt(8) (s+2,s+3 stay in flight) -> ~4-5-phase lead.
// LDS bank swizzle: phys 16B-chunk = chunk ^ ((row>>1)&3)  (2 lanes/bank = free);
// applied on the global SOURCE (linear gload_lds dest) and on the ds_read addr.
// All waitcnt asm carry "memory" clobbers; sched_barrier(0) pins segments.
// EPI: 0 bf16 store | 1 f32 +bias+res | 2 bf16 gelu(+bias) | 3 f32 +(bias?)+res
//      4 QKV split: col c -> outB + (c>>10)*TOK*1024, col c&1023

template <int EPI>
__global__ __launch_bounds__(512, 2)
void mgemm256_kernel(const ushort* __restrict__ A, const ushort* __restrict__ Bt,
                     const float* __restrict__ bias, const float* __restrict__ res,
                     float* __restrict__ outF, bf16* __restrict__ outB,
                     int M, int N, int K, int lda, int ldbt) {
  constexpr int SLOT = 256 * 32;       // ushorts per slot per operand (16 KiB)
  __shared__ ushort AsR[4][SLOT];
  __shared__ ushort BsR[4][SLOT];
  const int tid = threadIdx.x;
  const int wave = tid >> 6, lane = tid & 63;
  const int wr = wave >> 2, wc = wave & 3;
  const int mrow = lane & 15, quad = lane >> 4;

  int nn = gridDim.x, nm = gridDim.y;
  int bid = blockIdx.y * nn + blockIdx.x;
  int mtile, ntile;
  if ((nm & 7) == 0) {          // XCD swizzle (bijection; perf-only heuristic)
    int xcd = bid & 7, s = bid >> 3;
    int mpx = nm >> 3;
    int mloc = s / nn;
    ntile = s - mloc * nn;
    mtile = xcd * mpx + mloc;
  } else { mtile = blockIdx.y; ntile = blockIdx.x; }
  const int row0 = mtile * 256, col0 = ntile * 256;

  // ---- staging: linear LDS dest (l*8192B + tid*16B), inverse-swizzled source.
  // linear ushort L -> row = l*128 + (tid>>2), phys chunk = tid&3;
  // logical chunk = (tid&3) ^ ((row>>1)&3) = (tid&3) ^ ((tid>>3)&3).
  const int srowL = tid >> 2;                                   // 0..127
  const int sOff = (((tid & 3) ^ ((tid >> 3) & 3)) << 3);       // ushort units
  const ushort* aB = A + (size_t)(row0 + srowL) * lda + sOff;
  const ushort* bB = Bt + (size_t)(col0 + srowL) * ldbt + sOff;
  const int dst = tid * 8;                                      // ushort units

  auto stage = [&](int sg, int l) {
    const int sl = sg & 3;
    __builtin_amdgcn_global_load_lds(
        (const __attribute__((address_space(1))) void*)(aB + (size_t)(l * 128) * lda + sg * 32),
        (__attribute__((address_space(3))) void*)(&AsR[sl][l * 4096 + dst]), 16, 0, 0);
    __builtin_amdgcn_global_load_lds(
        (const __attribute__((address_space(1))) void*)(bB + (size_t)(l * 128) * ldbt + sg * 32),
        (__attribute__((address_space(3))) void*)(&BsR[sl][l * 4096 + dst]), 16, 0, 0);
  };

  // ds_read swizzled chunk offset (ushort units): (quad ^ ((mrow>>1)&3)) * 8
  const int cq = (quad << 3) ^ (((mrow >> 1) & 3) << 3);

  f32x4 acc[8][4] = {};
  const int NS = K >> 5;  // number of BK=32 sub-tiles

  // prologue: stage sub-tiles 0,1,2 (12 loads); wait for 0 (8 newest in flight)
  stage(0, 0); stage(0, 1); stage(1, 0); stage(1, 1); stage(2, 0); stage(2, 1);
  asm volatile("s_waitcnt vmcnt(8)" ::: "memory");
  __builtin_amdgcn_s_barrier();

  for (int sg = 0; sg < NS; ++sg) {
    const ushort* As_ = &AsR[sg & 3][0];
    const ushort* Bs_ = &BsR[sg & 3][0];
    short8 afv[4], bfv[4];
    // ================= phase A (MH=0) =================
#pragma unroll
    for (int i2 = 0; i2 < 4; ++i2)
      afv[i2] = *(const short8*)(As_ + (wr * 128 + i2 * 16 + mrow) * 32 + cq);
#pragma unroll
    for (int n = 0; n < 4; ++n)
      bfv[n] = *(const short8*)(Bs_ + (wc * 64 + (n >> 1) * 32 + (n & 1) * 16 + mrow) * 32 + cq);
    if (sg + 3 < NS) stage(sg + 3, 0);
    __builtin_amdgcn_sched_barrier(0);
    __builtin_amdgcn_s_barrier();
    asm volatile("s_waitcnt lgkmcnt(0)" ::: "memory");
    __builtin_amdgcn_sched_barrier(0);
    __builtin_amdgcn_s_setprio(1);
#pragma unroll
    for (int i2 = 0; i2 < 4; ++i2)
#pragma unroll
      for (int n = 0; n < 4; ++n)
        acc[i2][n] = __builtin_amdgcn_mfma_f32_16x16x32_bf16(afv[i2], bfv[n], acc[i2][n], 0, 0, 0);
    __builtin_amdgcn_s_setprio(0);
    __builtin_amdgcn_sched_barrier(0);
    __builtin_amdgcn_s_barrier();
    // ================= phase B (MH=1) =================
#pragma unroll
    for (int i2 = 0; i2 < 4; ++i2)
      afv[i2] = *(const short8*)(As_ + (wr * 128 + 64 + i2 * 16 + mrow) * 32 + cq);
    if (sg + 3 < NS) stage(sg + 3, 1);
    __builtin_amdgcn_sched_barrier(0);
    __builtin_amdgcn_s_barrier();
    asm volatile("s_waitcnt lgkmcnt(0)" ::: "memory");
    __builtin_amdgcn_sched_barrier(0);
    __builtin_amdgcn_s_setprio(1);
#pragma unroll
    for (int i2 = 0; i2 < 4; ++i2)
#pragma unroll
      for (int n = 0; n < 4; ++n)
        acc[4 + i2][n] = __builtin_amdgcn_mfma_f32_16x16x32_bf16(afv[i2], bfv[n], acc[4 + i2][n], 0, 0, 0);
    __builtin_amdgcn_s_setprio(0);
    // counted wait: sub-tile sg+1 must be resident; sg+2 (4) + sg+3 (4) in flight
    if (sg + 1 < NS) {
      if (sg + 3 < NS)      asm volatile("s_waitcnt vmcnt(8)" ::: "memory");
      else if (sg + 2 < NS) asm volatile("s_waitcnt vmcnt(4)" ::: "memory");
      else                  asm volatile("s_waitcnt vmcnt(0)" ::: "memory");
    }
    __builtin_amdgcn_sched_barrier(0);
    __builtin_amdgcn_s_barrier();
  }

  // epilogue
#pragma unroll
  for (int i = 0; i < 8; ++i) {
#pragma unroll
    for (int j = 0; j < 4; ++j) {
      int rb = row0 + wr * 128 + i * 16 + quad * 4;
      int c = col0 + wc * 64 + j * 16 + mrow;
#pragma unroll
      for (int r = 0; r < 4; ++r) {
        int rr = rb + r;
        float v = acc[i][j][r];
        if (EPI == 1 || EPI == 2) v += bias[c];
        if (EPI == 3) { if (bias) v += bias[c]; }
        if (EPI == 2) v = 0.5f * v * (1.f + erff(v * 0.70710678118654752f));
        if (EPI == 1 || EPI == 3) v += res[(size_t)rr * N + c];
        if (EPI == 4) {
          outB[((size_t)(c >> 10) * (size_t)(Bc * Sc) + rr) * 1024 + (c & 1023)] = f2b(v);
        } else if (EPI == 0 || EPI == 2) {
          outB[(size_t)rr * N + c] = f2b(v);
        } else {
          outF[(size_t)rr * N + c] = v;
        }
      }
    }
  }
}

// ======== fm_mfma: per-head [256s x 64] @ projT[64f][64d]^T, relu+eps ========
__global__ __launch_bounds__(256, 2)
void fm_mfma(const ushort* __restrict__ qin, const ushort* __restrict__ pjt,
             bf16* __restrict__ qf) {
  __shared__ ushort As[256 * 64];   // [s_local][d]
  __shared__ ushort Bs[64 * 64];    // [f][d]
  int t = threadIdx.x;
  int wave = t >> 6, lane = t & 63;
  int mrow = lane & 15, quad = lane >> 4;
  int b = blockIdx.z, h = blockIdx.y, s0 = blockIdx.x * 256;
  const ushort* abase = qin + ((size_t)b * Sc + s0) * (Hc * DHc) + h * DHc;

#pragma unroll
  for (int i = 0; i < 8; ++i) {
    int c = t + 256 * i;
    int row = c >> 3, col = (c & 7) * 8;
    __builtin_amdgcn_global_load_lds(
        (const __attribute__((address_space(1))) void*)(abase + (size_t)row * (Hc * DHc) + col),
        (__attribute__((address_space(3))) void*)(As + c * 8), 16, 0, 0);
  }
#pragma unroll
  for (int i = 0; i < 2; ++i) {
    int c = t + 256 * i;
    __builtin_amdgcn_global_load_lds(
        (const __attribute__((address_space(1))) void*)(pjt + c * 8),
        (__attribute__((address_space(3))) void*)(Bs + c * 8), 16, 0, 0);
  }
  __syncthreads();

  f32x4 acc[4][4] = {};
#pragma unroll
  for (int step = 0; step < 2; ++step) {
    short8 af[4], bfv[4];
#pragma unroll
    for (int i = 0; i < 4; ++i)
      af[i] = *(const short8*)(As + (wave * 64 + i * 16 + mrow) * 64 + quad * 8 + step * 32);
#pragma unroll
    for (int j = 0; j < 4; ++j)
      bfv[j] = *(const short8*)(Bs + (j * 16 + mrow) * 64 + quad * 8 + step * 32);
#pragma unroll
    for (int i = 0; i < 4; ++i)
#pragma unroll
      for (int j = 0; j < 4; ++j)
        acc[i][j] = __builtin_amdgcn_mfma_f32_16x16x32_bf16(af[i], bfv[j], acc[i][j], 0, 0, 0);
  }

  size_t obase = ((size_t)(b * Hc + h)) * Sc + s0;
#pragma unroll
  for (int i = 0; i < 4; ++i) {
#pragma unroll
    for (int j = 0; j < 4; ++j) {
      int f = j * 16 + mrow;
#pragma unroll
      for (int r = 0; r < 4; ++r) {
        int s = wave * 64 + i * 16 + quad * 4 + r;
        float v = fmaxf(acc[i][j][r], 0.f) + EPS_ATTN_C;
        qf[(obase + s) * Fc + f] = f2b(v);
      }
    }
  }
}

// ======== kvp_mfma: split-K kf^T v (+ ksum) via LDS transpose ========
__global__ __launch_bounds__(256, 2)
void kvp_mfma(const ushort* __restrict__ kf, const ushort* __restrict__ v,
              float* __restrict__ kvp, float* __restrict__ ksump) {
  constexpr int LT = 72;
  __shared__ ushort kfT[64 * LT];   // [f][s]
  __shared__ ushort vT[64 * LT];    // [d][s]
  int t = threadIdx.x;
  int wave = t >> 6, lane = t & 63;
  int mrow = lane & 15, quad = lane >> 4;
  int split = blockIdx.x, bh = blockIdx.y;
  int b = bh >> 4, h = bh & 15;
  int sbase = split * (Sc / KVSPLIT);

  short8 ones, zero;
#pragma unroll
  for (int i = 0; i < 8; ++i) { ones[i] = (short)0x3F80; zero[i] = 0; }
  short8 bks = (mrow == 0) ? ones : zero;

  f32x4 acc[4] = {};
  f32x4 accks = {};

  for (int sc = 0; sc < Sc / KVSPLIT; sc += 64) {
    __syncthreads();
    int sl = t >> 2, c8 = (t & 3) * 8;
    const ushort* kp = kf + (((size_t)bh * Sc) + sbase + sc + sl) * Fc + c8;
    const ushort* vp = v + (((size_t)b * Sc) + sbase + sc + sl) * (Hc * DHc) + h * DHc + c8;
#pragma unroll
    for (int half = 0; half < 2; ++half) {
      short8 kv8 = *(const short8*)(kp + half * 32);
      short8 vv8 = *(const short8*)(vp + half * 32);
#pragma unroll
      for (int jj = 0; jj < 8; ++jj) {
        kfT[(c8 + half * 32 + jj) * LT + sl] = (ushort)kv8[jj];
        vT[(c8 + half * 32 + jj) * LT + sl] = (ushort)vv8[jj];
      }
    }
    __syncthreads();
#pragma unroll
    for (int step = 0; step < 2; ++step) {
      short8 af = *(const short8*)(kfT + (wave * 16 + mrow) * LT + quad * 8 + step * 32);
      short8 bfv[4];
#pragma unroll
      for (int j = 0; j < 4; ++j)
        bfv[j] = *(const short8*)(vT + (j * 16 + mrow) * LT + quad * 8 + step * 32);
#pragma unroll
      for (int j = 0; j < 4; ++j)
        acc[j] = __builtin_amdgcn_mfma_f32_16x16x32_bf16(af, bfv[j], acc[j], 0, 0, 0);
      accks = __builtin_amdgcn_mfma_f32_16x16x32_bf16(af, bks, accks, 0, 0, 0);
    }
  }

  size_t pbase = (size_t)bh * KVSPLIT + split;
#pragma unroll
  for (int j = 0; j < 4; ++j) {
    int d = j * 16 + mrow;
#pragma unroll
    for (int r = 0; r < 4; ++r) {
      int f = wave * 16 + quad * 4 + r;
      kvp[(pbase * 64 + f) * 64 + d] = acc[j][r];
    }
  }
  if (mrow == 0) {
#pragma unroll
    for (int r = 0; r < 4; ++r) {
      int f = wave * 16 + quad * 4 + r;
      ksump[pbase * 64 + f] = accks[r];
    }
  }
}

// ------- kv reduce: sums KVSPLIT partials -> kvt bf16 [d][f], ksum bf16 -------
__global__ void kvr_kernel(const float* __restrict__ kvp, const float* __restrict__ ksump,
                           bf16* __restrict__ kvt, bf16* __restrict__ ksum16) {
  int bh = blockIdx.x;
  int t = threadIdx.x;
#pragma unroll
  for (int i = 0; i < 16; ++i) {
    int idx = t + 256 * i;
    int f = idx >> 6, d = idx & 63;
    float s = 0.f;
#pragma unroll
    for (int j = 0; j < KVSPLIT; ++j)
      s += kvp[((size_t)bh * KVSPLIT + j) * 4096 + idx];
    kvt[((size_t)bh * 64 + d) * 64 + f] = f2b(s);
  }
  if (t < 64) {
    float s = 0.f;
#pragma unroll
    for (int j = 0; j < KVSPLIT; ++j)
      s += ksump[((size_t)bh * KVSPLIT + j) * 64 + t];
    ksum16[bh * 64 + t] = f2b(s);
  }
}

// ======== attn_mfma: per-head (qf @ kv) / (qf.ksum + eps) ========
__global__ __launch_bounds__(256, 2)
void attn_mfma(const ushort* __restrict__ qf, const ushort* __restrict__ kvt,
               const ushort* __restrict__ ksum16, bf16* __restrict__ attn) {
  __shared__ ushort As[256 * 64];   // [s_local][f]
  __shared__ ushort Bs[64 * 64];    // [d][f]
  int t = threadIdx.x;
  int wave = t >> 6, lane = t & 63;
  int mrow = lane & 15, quad = lane >> 4;
  int b = blockIdx.z, h = blockIdx.y, s0 = blockIdx.x * 256;
  int bh = b * Hc + h;
  const ushort* abase = qf + (((size_t)bh * Sc) + s0) * Fc;
  const ushort* bbase = kvt + (size_t)bh * 4096;

#pragma unroll
  for (int i = 0; i < 8; ++i) {
    int c = t + 256 * i;
    __builtin_amdgcn_global_load_lds(
        (const __attribute__((address_space(1))) void*)(abase + c * 8),
        (__attribute__((address_space(3))) void*)(As + c * 8), 16, 0, 0);
  }
#pragma unroll
  for (int i = 0; i < 2; ++i) {
    int c = t + 256 * i;
    __builtin_amdgcn_global_load_lds(
        (const __attribute__((address_space(1))) void*)(bbase + c * 8),
        (__attribute__((address_space(3))) void*)(Bs + c * 8), 16, 0, 0);
  }
  short8 zero;
#pragma unroll
  for (int i = 0; i < 8; ++i) zero[i] = 0;
  short8 ksf[2];
#pragma unroll
  for (int step = 0; step < 2; ++step) {
    short8 kv8 = *(const short8*)(ksum16 + bh * 64 + quad * 8 + step * 32);
    ksf[step] = (mrow == 0) ? kv8 : zero;
  }
  __syncthreads();

  f32x4 acc[4][4] = {};
  f32x4 accd[4] = {};
#pragma unroll
  for (int step = 0; step < 2; ++step) {
    short8 af[4], bfv[4];
#pragma unroll
    for (int i = 0; i < 4; ++i)
      af[i] = *(const short8*)(As + (wave * 64 + i * 16 + mrow) * 64 + quad * 8 + step * 32);
#pragma unroll
    for (int j = 0; j < 4; ++j)
      bfv[j] = *(const short8*)(Bs + (j * 16 + mrow) * 64 + quad * 8 + step * 32);
#pragma unroll
    for (int i = 0; i < 4; ++i) {
#pragma unroll
      for (int j = 0; j < 4; ++j)
        acc[i][j] = __builtin_amdgcn_mfma_f32_16x16x32_bf16(af[i], bfv[j], acc[i][j], 0, 0, 0);
      accd[i] = __builtin_amdgcn_mfma_f32_16x16x32_bf16(af[i], ksf[step], accd[i], 0, 0, 0);
    }
  }

#pragma unroll
  for (int i = 0; i < 4; ++i) {
    float inv[4];
#pragma unroll
    for (int r = 0; r < 4; ++r) {
      float den = __shfl(accd[i][r], lane & 48);
      inv[r] = 1.0f / (den + EPS_ATTN_C);
    }
#pragma unroll
    for (int j = 0; j < 4; ++j) {
      int d = j * 16 + mrow;
#pragma unroll
      for (int r = 0; r < 4; ++r) {
        int s = s0 + wave * 64 + i * 16 + quad * 4 + r;
        attn[((size_t)(b * Sc + s)) * (Hc * DHc) + h * DHc + d] = f2b(acc[i][j][r] * inv[r]);
      }
    }
  }
}

extern "C" void kernel_launch(void* const* d_in, const int* in_sizes, int n_in,
                              void* d_out, int out_size, void* d_ws, size_t ws_size,
                              hipStream_t stream) {
  const float* x     = (const float*)d_in[0];
  const float* ln1_g = (const float*)d_in[1];
  const float* ln1_b = (const float*)d_in[2];
  const float* wq    = (const float*)d_in[3];
  const float* wk    = (const float*)d_in[4];
  const float* wv    = (const float*)d_in[5];
  const float* proj  = (const float*)d_in[6];
  const float* wo    = (const float*)d_in[7];
  const float* bo    = (const float*)d_in[8];
  const float* ln2_g = (const float*)d_in[9];
  const float* ln2_b = (const float*)d_in[10];
  const float* w1    = (const float*)d_in[11];
  const float* b1    = (const float*)d_in[12];
  const float* w2    = (const float*)d_in[13];
  const float* b2    = (const float*)d_in[14];
  float* out = (float*)d_out;
  (void)ws_size; (void)in_sizes; (void)n_in; (void)out_size;

  const size_t TOK = (size_t)Bc * Sc;           // 16384
  const size_t REG = TOK * Dc * sizeof(bf16);   // 32 MB
  char* ws = (char*)d_ws;
  bf16* R0 = (bf16*)(ws + 0 * REG);             // h -> qf -> h2
  bf16* R1 = (bf16*)(ws + 1 * REG);             // q -> kf -> mid(lo)
  bf16* R2 = (bf16*)(ws + 2 * REG);             // k -> [kv partials] -> attn -> mid(hi)
  bf16* R3 = (bf16*)(ws + 3 * REG);             // v
  bf16* mid = R1;
  float* kvpart = (float*)R2;                                   // 16 MB (aliases R2)
  float* kspart = (float*)((char*)R2 + (size_t)64 * KVSPLIT * 4096 * 4);
  char* p = ws + 4 * REG;
  bf16* kvt   = (bf16*)p;                 p += (size_t)64 * 64 * 64 * 2;
  bf16* ksb16 = (bf16*)p;                 p += (size_t)64 * 64 * 2;
  bf16* pjt   = (bf16*)p;                 p += (size_t)64 * 64 * 2;
  bf16* wqt = (bf16*)p;                   p += (size_t)Dc * Dc * 2;   // wqt/wkt/wvt contiguous:
  bf16* wkt = (bf16*)p;                   p += (size_t)Dc * Dc * 2;   // single [3072][1024] Bt slab
  bf16* wvt = (bf16*)p;                   p += (size_t)Dc * Dc * 2;
  bf16* wot = (bf16*)p;                   p += (size_t)Dc * Dc * 2;
  bf16* w1t = (bf16*)p;                   p += (size_t)Dc * DFFc * 2;
  bf16* w2t = (bf16*)p;                   p += (size_t)Dc * DFFc * 2;

  dim3 blk(256);
  dim3 blk512(512);
  // 0. transpose+convert weights (and proj) to bf16 B^T form
  tcvt_kernel<<<dim3(Dc / 32, Dc / 32), blk, 0, stream>>>(wq, wqt, Dc, Dc);
  tcvt_kernel<<<dim3(Dc / 32, Dc / 32), blk, 0, stream>>>(wk, wkt, Dc, Dc);
  tcvt_kernel<<<dim3(Dc / 32, Dc / 32), blk, 0, stream>>>(wv, wvt, Dc, Dc);
  tcvt_kernel<<<dim3(Dc / 32, Dc / 32), blk, 0, stream>>>(wo, wot, Dc, Dc);
  tcvt_kernel<<<dim3(DFFc / 32, Dc / 32), blk, 0, stream>>>(w1, w1t, Dc, DFFc);
  tcvt_kernel<<<dim3(Dc / 32, DFFc / 32), blk, 0, stream>>>(w2, w2t, DFFc, Dc);
  tcvt_kernel<<<dim3(2, 2), blk, 0, stream>>>(proj, pjt, 64, 64);

  // 1. h = LN1(x) -> R0
  ln_kernel<<<dim3(TOK), blk, 0, stream>>>(x, ln1_g, ln1_b, R0);

  // 2. fused QKV: [TOK,1024] @ [3072,1024]^T -> split into R1,R2,R3 (EPI=4)
  dim3 gQKV(3072 / 256, TOK / 256);
  mgemm256_kernel<4><<<gQKV, blk512, 0, stream>>>((const ushort*)R0, (const ushort*)wqt,
                                                  nullptr, nullptr, nullptr, R1,
                                                  TOK, 3072, Dc, Dc, Dc);

  // 5-6. qf = fm(q): R1 -> R0 ; kf = fm(k): R2 -> R1
  dim3 gF(Sc / 256, Hc, Bc);
  fm_mfma<<<gF, blk, 0, stream>>>((const ushort*)R1, (const ushort*)pjt, R0);
  fm_mfma<<<gF, blk, 0, stream>>>((const ushort*)R2, (const ushort*)pjt, R1);

  // 7. kv partials + reduce
  kvp_mfma<<<dim3(KVSPLIT, Bc * Hc), blk, 0, stream>>>((const ushort*)R1, (const ushort*)R3,
                                                       kvpart, kspart);
  kvr_kernel<<<dim3(Bc * Hc), blk, 0, stream>>>(kvpart, kspart, kvt, ksb16);

  // 8. attn: qf(R0) x kvt -> R2
  attn_mfma<<<gF, blk, 0, stream>>>((const ushort*)R0, (const ushort*)kvt,
                                    (const ushort*)ksb16, R2);

  // 9. x2 = x + attn @ wo + bo -> d_out (f32)
  dim3 gD(Dc / 256, TOK / 256);
  mgemm256_kernel<1><<<gD, blk512, 0, stream>>>((const ushort*)R2, (const ushort*)wot, bo, x,
                                                out, nullptr, TOK, Dc, Dc, Dc, Dc);

  // 10. h2 = LN2(x2) -> R0
  ln_kernel<<<dim3(TOK), blk, 0, stream>>>(out, ln2_g, ln2_b, R0);

  // 11-12. FFN in two DFF halves (mid aliases R1+R2)
  dim3 gW1(2048 / 256, TOK / 256);
  mgemm256_kernel<2><<<gW1, blk512, 0, stream>>>((const ushort*)R0, (const ushort*)w1t, b1, nullptr,
                                                 nullptr, mid, TOK, 2048, Dc, Dc, Dc);
  mgemm256_kernel<3><<<gD, blk512, 0, stream>>>((const ushort*)mid, (const ushort*)w2t, b2, out,
                                                out, nullptr, TOK, Dc, 2048, 2048, DFFc);
  mgemm256_kernel<2><<<gW1, blk512, 0, stream>>>((const ushort*)R0, (const ushort*)(w1t + (size_t)2048 * Dc), b1 + 2048,
                                                 nullptr, nullptr, mid, TOK, 2048, Dc, Dc, Dc);
  mgemm256_kernel<3><<<gD, blk512, 0, stream>>>((const ushort*)mid, (const ushort*)(w2t + 2048), nullptr, out,
                                                out, nullptr, TOK, Dc, 2048, 2048, DFFc);
}